// Round 4
// baseline (955.695 us; speedup 1.0000x reference)
//
#include <hip/hip_runtime.h>
#include <hip/hip_bf16.h>

typedef __bf16 bf16;
typedef __bf16 bf16x8 __attribute__((ext_vector_type(8)));
typedef float f32x4 __attribute__((ext_vector_type(4)));
typedef float floatv4 __attribute__((ext_vector_type(4)));

#define QK_SCALE 0.17677669529663687f

// ---- swizzled LDS addressing -------------------------------------------------
// qp/k tiles: [64][32] bf16 per head (row = 64B = 4 x 16B chunks).
__device__ __forceinline__ bf16* qk_ptr(bf16* base, int row, int col) {
    return base + row * 32 + ((((col >> 3) ^ ((row >> 1) & 3)) << 3)) + (col & 7);
}
// vt tile: [32][64] bf16 per head (row = 128B = 8 chunks). chunk' = chunk ^ (row&7).
__device__ __forceinline__ bf16* vt_ptr(bf16* base, int row, int col) {
    return base + row * 64 + ((((col >> 3) ^ (row & 7)) << 3)) + (col & 7);
}
// ao tile: [64][192] bf16 (row = 384B = 24 chunks). chunk' = chunk ^ (row&7).
__device__ __forceinline__ bf16* ao_ptr(bf16* base, int row, int col) {
    return base + row * 192 + ((((col >> 3) ^ (row & 7)) << 3)) + (col & 7);
}

// ---------------- prep: weight bf16 convert + rpb expand + combo table --------
__global__ void wmsa_prep(const float* __restrict__ qkv_w,
                          const float* __restrict__ out_w,
                          const float* __restrict__ rpb_table,
                          const float* __restrict__ mask,
                          bf16* __restrict__ qkv_wb,
                          bf16* __restrict__ out_wb,
                          float* __restrict__ rpbx,
                          float* __restrict__ combo,
                          int build_combo) {
    int t = blockIdx.x * 256 + threadIdx.x;
    if (t < 110592) qkv_wb[t] = (bf16)qkv_w[t];
    if (t < 36864)  out_wb[t] = (bf16)out_w[t];
    if (t < 14406) {
        int h = t / 2401, ij = t % 2401, i = ij / 49, j = ij % 49;
        int ri = (i / 7 - j / 7 + 6) * 13 + (i % 7 - j % 7 + 6);
        rpbx[t] = rpb_table[ri * 6 + h];
    }
    if (build_combo && t < 64 * 6 * 64 * 64) {
        int j = t & 63, i = (t >> 6) & 63, r = t >> 12;
        int h = r % 6, w = r / 6;
        float v = -1e30f;
        if (i < 49 && j < 49) {
            int ri = (i / 7 - j / 7 + 6) * 13 + (i % 7 - j % 7 + 6);
            v = rpb_table[ri * 6 + h] + mask[w * 2401 + i * 49 + j];
        }
        combo[t] = v;
    }
}

// ---------------- main fused kernel: one window per block ----------------
template <bool USE_COMBO>
__global__ __launch_bounds__(384, 3) void wmsa_main(
    const float* __restrict__ x, const float* __restrict__ mask,
    const float* __restrict__ qkv_b, const float* __restrict__ out_b,
    const bf16* __restrict__ qkv_wb, const bf16* __restrict__ out_wb,
    const float* __restrict__ rpbx, const float* __restrict__ combo,
    float* __restrict__ out)
{
    // q (later p): 6 heads x [64][32]; k (later ao[64][192]); v^T: 6 x [32][64]
    __shared__ bf16 s_qp[6][2048];
    __shared__ bf16 s_kao[12288];
    __shared__ bf16 s_vt[6][2048];

    const int b    = blockIdx.x;
    const int tid  = threadIdx.x;
    const int wv   = tid >> 6;      // 0..5
    const int lane = tid & 63;
    const int lo   = lane & 15;
    const int hi   = lane >> 4;     // 0..3

    const float* xw    = x + (size_t)b * 9408;
    const int    obase = wv * 96;
    const int    sec   = wv >> 1;   // 0=q 1=k 2=v

    // ============ Phase 1: QKV = x @ qkv_w^T + qkv_b ============
#pragma unroll 1
    for (int mib = 0; mib < 2; ++mib) {
        f32x4 acc[2][6];
#pragma unroll
        for (int mi = 0; mi < 2; ++mi)
#pragma unroll
            for (int nj = 0; nj < 6; ++nj) acc[mi][nj] = (f32x4){0.f, 0.f, 0.f, 0.f};

        const int r0 = mib * 32 + lo;        // always < 49
        const int r1 = r0 + 16;              // mib=1: valid only if < 49

        auto loadA = [&](bf16x8& d0, bf16x8& d1, int kk) {
            const float* p0 = xw + r0 * 192 + kk * 32 + hi * 8;
            floatv4 f0 = *(const floatv4*)p0;
            floatv4 f1 = *(const floatv4*)(p0 + 4);
            d0[0]=(bf16)f0[0]; d0[1]=(bf16)f0[1]; d0[2]=(bf16)f0[2]; d0[3]=(bf16)f0[3];
            d0[4]=(bf16)f1[0]; d0[5]=(bf16)f1[1]; d0[6]=(bf16)f1[2]; d0[7]=(bf16)f1[3];
            floatv4 g0 = {0.f,0.f,0.f,0.f}, g1 = {0.f,0.f,0.f,0.f};
            if (r1 < 49) {
                const float* p1 = xw + r1 * 192 + kk * 32 + hi * 8;
                g0 = *(const floatv4*)p1;
                g1 = *(const floatv4*)(p1 + 4);
            }
            d1[0]=(bf16)g0[0]; d1[1]=(bf16)g0[1]; d1[2]=(bf16)g0[2]; d1[3]=(bf16)g0[3];
            d1[4]=(bf16)g1[0]; d1[5]=(bf16)g1[1]; d1[6]=(bf16)g1[2]; d1[7]=(bf16)g1[3];
        };

        bf16x8 a0, a1, na0, na1;
        loadA(a0, a1, 0);
#pragma unroll
        for (int kk = 0; kk < 6; ++kk) {
            if (kk < 5) loadA(na0, na1, kk + 1);
#pragma unroll
            for (int nj = 0; nj < 6; ++nj) {
                const int o = obase + nj * 16 + lo;
                bf16x8 bfr = *(const bf16x8*)(qkv_wb + o * 192 + kk * 32 + hi * 8);
                acc[0][nj] = __builtin_amdgcn_mfma_f32_16x16x32_bf16(a0, bfr, acc[0][nj], 0, 0, 0);
                acc[1][nj] = __builtin_amdgcn_mfma_f32_16x16x32_bf16(a1, bfr, acc[1][nj], 0, 0, 0);
            }
            a0 = na0; a1 = na1;
        }

        // epilogue: bias + scatter into q / k / v^T LDS tiles
#pragma unroll
        for (int nj = 0; nj < 6; ++nj) {
            const int o    = obase + nj * 16 + lo;
            const float bs = qkv_b[o];
            const int oc   = o - sec * 192;
            const int hh   = oc >> 5;
            const int dd   = oc & 31;
#pragma unroll
            for (int mi = 0; mi < 2; ++mi)
#pragma unroll
                for (int r = 0; r < 4; ++r) {
                    const int n = mib * 32 + mi * 16 + hi * 4 + r;
                    const float v = acc[mi][nj][r] + bs;
                    if (sec == 0)      *qk_ptr(&s_qp[hh][0], n, dd)      = (bf16)(v * QK_SCALE);
                    else if (sec == 1) *qk_ptr(s_kao + hh * 2048, n, dd) = (bf16)v;
                    else               *vt_ptr(&s_vt[hh][0], dd, n)      = (bf16)v;
                }
        }
    }
    __syncthreads();

    // ============ Phase 2: attention, head h = wave id, 2 passes of 32 rows ===
    {
        const int h = wv;
        bf16* qb = &s_qp[h][0];
        bf16* kbase = s_kao + h * 2048;
        const float* cb = combo + (((size_t)(b & 63) * 6 + h) << 12);
        const float* mk = mask + (size_t)(b & 63) * 2401;
        const float* rb = rpbx + h * 2401;

        f32x4 oacc[2][2][2];   // [pass][mi][nd]
#pragma unroll
        for (int p = 0; p < 2; ++p)
#pragma unroll
            for (int mi = 0; mi < 2; ++mi)
#pragma unroll
                for (int nd = 0; nd < 2; ++nd) oacc[p][mi][nd] = (f32x4){0.f, 0.f, 0.f, 0.f};

#pragma unroll
        for (int p = 0; p < 2; ++p) {
            const int rowb = p * 32;
            bf16x8 qa0 = *(const bf16x8*)qk_ptr(qb, rowb + lo, hi * 8);
            bf16x8 qa1 = *(const bf16x8*)qk_ptr(qb, rowb + 16 + lo, hi * 8);
            bf16x8 kb0 = *(const bf16x8*)qk_ptr(kbase, 0 + lo, hi * 8);
            bf16x8 kb1 = *(const bf16x8*)qk_ptr(kbase, 16 + lo, hi * 8);
            bf16x8 kb2 = *(const bf16x8*)qk_ptr(kbase, 32 + lo, hi * 8);
            bf16x8 kb3 = *(const bf16x8*)qk_ptr(kbase, 48 + lo, hi * 8);

            f32x4 s[2][4];
#pragma unroll
            for (int mi = 0; mi < 2; ++mi)
#pragma unroll
                for (int nt = 0; nt < 4; ++nt) s[mi][nt] = (f32x4){0.f, 0.f, 0.f, 0.f};
            s[0][0] = __builtin_amdgcn_mfma_f32_16x16x32_bf16(qa0, kb0, s[0][0], 0, 0, 0);
            s[0][1] = __builtin_amdgcn_mfma_f32_16x16x32_bf16(qa0, kb1, s[0][1], 0, 0, 0);
            s[0][2] = __builtin_amdgcn_mfma_f32_16x16x32_bf16(qa0, kb2, s[0][2], 0, 0, 0);
            s[0][3] = __builtin_amdgcn_mfma_f32_16x16x32_bf16(qa0, kb3, s[0][3], 0, 0, 0);
            s[1][0] = __builtin_amdgcn_mfma_f32_16x16x32_bf16(qa1, kb0, s[1][0], 0, 0, 0);
            s[1][1] = __builtin_amdgcn_mfma_f32_16x16x32_bf16(qa1, kb1, s[1][1], 0, 0, 0);
            s[1][2] = __builtin_amdgcn_mfma_f32_16x16x32_bf16(qa1, kb2, s[1][2], 0, 0, 0);
            s[1][3] = __builtin_amdgcn_mfma_f32_16x16x32_bf16(qa1, kb3, s[1][3], 0, 0, 0);

            // bias + mask
            if (USE_COMBO) {
#pragma unroll
                for (int nt = 0; nt < 4; ++nt) {
                    const int j = nt * 16 + lo;
#pragma unroll
                    for (int mi = 0; mi < 2; ++mi)
#pragma unroll
                        for (int r = 0; r < 4; ++r) {
                            const int i = rowb + mi * 16 + hi * 4 + r;
                            s[mi][nt][r] += cb[i * 64 + j];
                        }
                }
            } else {
#pragma unroll
                for (int nt = 0; nt < 4; ++nt) {
                    const int j = nt * 16 + lo;
#pragma unroll
                    for (int mi = 0; mi < 2; ++mi)
#pragma unroll
                        for (int r = 0; r < 4; ++r) {
                            const int i = rowb + mi * 16 + hi * 4 + r;
                            float sv = s[mi][nt][r];
                            if (j >= 49 || i >= 49) sv = -1e30f;
                            else sv += rb[i * 49 + j] + mk[i * 49 + j];
                            s[mi][nt][r] = sv;
                        }
                }
            }

            // softmax over j
#pragma unroll
            for (int mi = 0; mi < 2; ++mi)
#pragma unroll
                for (int r = 0; r < 4; ++r) {
                    float m = fmaxf(fmaxf(s[mi][0][r], s[mi][1][r]),
                                    fmaxf(s[mi][2][r], s[mi][3][r]));
                    m = fmaxf(m, __shfl_xor(m, 1));
                    m = fmaxf(m, __shfl_xor(m, 2));
                    m = fmaxf(m, __shfl_xor(m, 4));
                    m = fmaxf(m, __shfl_xor(m, 8));
                    float sum = 0.f;
#pragma unroll
                    for (int nt = 0; nt < 4; ++nt) {
                        float pv = __expf(s[mi][nt][r] - m);
                        s[mi][nt][r] = pv;
                        sum += pv;
                    }
                    sum += __shfl_xor(sum, 1);
                    sum += __shfl_xor(sum, 2);
                    sum += __shfl_xor(sum, 4);
                    sum += __shfl_xor(sum, 8);
                    const float inv = 1.0f / sum;
#pragma unroll
                    for (int nt = 0; nt < 4; ++nt) s[mi][nt][r] *= inv;
                }

            // PV for this pass: stage P (32 x 64) in two 32-col chunks over
            // the pass's own q rows (already consumed).
#pragma unroll
            for (int kk = 0; kk < 2; ++kk) {
#pragma unroll
                for (int mi = 0; mi < 2; ++mi)
#pragma unroll
                    for (int c = 0; c < 2; ++c) {
                        const int nt = kk * 2 + c;
#pragma unroll
                        for (int r = 0; r < 4; ++r)
                            *qk_ptr(qb, rowb + mi * 16 + hi * 4 + r, c * 16 + lo) =
                                (bf16)s[mi][nt][r];
                    }
                bf16x8 pa0 = *(const bf16x8*)qk_ptr(qb, rowb + lo, hi * 8);
                bf16x8 pa1 = *(const bf16x8*)qk_ptr(qb, rowb + 16 + lo, hi * 8);
#pragma unroll
                for (int nd = 0; nd < 2; ++nd) {
                    bf16x8 vb = *(const bf16x8*)vt_ptr(&s_vt[h][0], nd * 16 + lo, kk * 32 + hi * 8);
                    oacc[p][0][nd] = __builtin_amdgcn_mfma_f32_16x16x32_bf16(pa0, vb, oacc[p][0][nd], 0, 0, 0);
                    oacc[p][1][nd] = __builtin_amdgcn_mfma_f32_16x16x32_bf16(pa1, vb, oacc[p][1][nd], 0, 0, 0);
                }
            }
        }

        // all waves' k/vt LDS reads happened before this point -> overlay safe
        __syncthreads();

        // scatter head output into ao (overlays k)
#pragma unroll
        for (int p = 0; p < 2; ++p)
#pragma unroll
            for (int mi = 0; mi < 2; ++mi)
#pragma unroll
                for (int nd = 0; nd < 2; ++nd)
#pragma unroll
                    for (int r = 0; r < 4; ++r)
                        *ao_ptr(s_kao, p * 32 + mi * 16 + hi * 4 + r,
                                h * 32 + nd * 16 + lo) = (bf16)oacc[p][mi][nd][r];
    }
    __syncthreads();

    // ============ Phase 3: out = ao @ out_w^T + out_b ============
    {
        f32x4 facc[2][4];
#pragma unroll
        for (int t2 = 0; t2 < 2; ++t2)
#pragma unroll
            for (int mi = 0; mi < 4; ++mi) facc[t2][mi] = (f32x4){0.f, 0.f, 0.f, 0.f};

#pragma unroll
        for (int kk = 0; kk < 6; ++kk) {
            bf16x8 fa[4];
#pragma unroll
            for (int mi = 0; mi < 4; ++mi)
                fa[mi] = *(const bf16x8*)ao_ptr(s_kao, mi * 16 + lo, kk * 32 + hi * 8);
            bf16x8 fb0 = *(const bf16x8*)(out_wb + ((wv * 2 + 0) * 16 + lo) * 192 + kk * 32 + hi * 8);
            bf16x8 fb1 = *(const bf16x8*)(out_wb + ((wv * 2 + 1) * 16 + lo) * 192 + kk * 32 + hi * 8);
#pragma unroll
            for (int mi = 0; mi < 4; ++mi) {
                facc[0][mi] = __builtin_amdgcn_mfma_f32_16x16x32_bf16(fa[mi], fb0, facc[0][mi], 0, 0, 0);
                facc[1][mi] = __builtin_amdgcn_mfma_f32_16x16x32_bf16(fa[mi], fb1, facc[1][mi], 0, 0, 0);
            }
        }

        float* ow = out + (size_t)b * 9408;
#pragma unroll
        for (int t2 = 0; t2 < 2; ++t2) {
            const int o2 = (wv * 2 + t2) * 16 + lo;
            const float ob = out_b[o2];
#pragma unroll
            for (int mi = 0; mi < 4; ++mi)
#pragma unroll
                for (int r = 0; r < 4; ++r) {
                    const int n = mi * 16 + hi * 4 + r;
                    if (n < 49) ow[n * 192 + o2] = facc[t2][mi][r] + ob;
                }
        }
    }
}

extern "C" void kernel_launch(void* const* d_in, const int* in_sizes, int n_in,
                              void* d_out, int out_size, void* d_ws, size_t ws_size,
                              hipStream_t stream) {
    const float* x      = (const float*)d_in[0];
    const float* mask   = (const float*)d_in[1];
    const float* qkv_w  = (const float*)d_in[2];
    const float* qkv_b  = (const float*)d_in[3];
    const float* out_w  = (const float*)d_in[4];
    const float* out_b  = (const float*)d_in[5];
    const float* rpb    = (const float*)d_in[6];
    float* out          = (float*)d_out;

    char* ws = (char*)d_ws;
    bf16*  qkv_wb = (bf16*)ws;                       // 110592 * 2 = 221184 B
    bf16*  out_wb = (bf16*)(ws + 221184);            //  36864 * 2 =  73728 B
    float* rpbx   = (float*)(ws + 294912);           //  14406 * 4 =  57624 B
    float* combo  = (float*)(ws + 352768);           // 1572864 * 4 = 6291456 B
    const bool use_combo = ws_size >= (size_t)(352768 + 6291456);

    hipLaunchKernelGGL(wmsa_prep, dim3(6144), dim3(256), 0, stream,
                       qkv_w, out_w, rpb, mask, qkv_wb, out_wb, rpbx, combo,
                       use_combo ? 1 : 0);
    if (use_combo)
        hipLaunchKernelGGL(HIP_KERNEL_NAME(wmsa_main<true>), dim3(4096), dim3(384), 0, stream,
                           x, mask, qkv_b, out_b, qkv_wb, out_wb, rpbx, combo, out);
    else
        hipLaunchKernelGGL(HIP_KERNEL_NAME(wmsa_main<false>), dim3(4096), dim3(384), 0, stream,
                           x, mask, qkv_b, out_b, qkv_wb, out_wb, rpbx, combo, out);
}

// Round 5
// 598.431 us; speedup vs baseline: 1.5970x; 1.5970x over previous
//
#include <hip/hip_runtime.h>
#include <hip/hip_bf16.h>

typedef __bf16 bf16;
typedef __bf16 bf16x8 __attribute__((ext_vector_type(8)));
typedef float f32x4 __attribute__((ext_vector_type(4)));
typedef float floatv4 __attribute__((ext_vector_type(4)));

#define QK_SCALE 0.17677669529663687f

// ---- swizzled LDS addressing -------------------------------------------------
// qp/k tiles: [64][32] bf16 per head (row = 64B = 4 x 16B chunks).
__device__ __forceinline__ bf16* qk_ptr(bf16* base, int row, int col) {
    return base + row * 32 + ((((col >> 3) ^ ((row >> 1) & 3)) << 3)) + (col & 7);
}
// vt tile: [32][64] bf16 per head (row = 128B = 8 chunks). chunk' = chunk ^ (row&7).
__device__ __forceinline__ bf16* vt_ptr(bf16* base, int row, int col) {
    return base + row * 64 + ((((col >> 3) ^ (row & 7)) << 3)) + (col & 7);
}
// ao tile in K2 LDS: [64][192] bf16, 16B chunk index cc=col>>3 in 0..23,
// swizzled chunk = cc ^ (row&7) (stays inside its 8-chunk group).
__device__ __forceinline__ bf16* ao_ptr(bf16* base, int row, int col) {
    return base + row * 192 + ((((col >> 3) ^ (row & 7)) << 3)) + (col & 7);
}

// ---------------- prep: weight bf16 convert + rpb expand + combo table --------
__global__ void wmsa_prep(const float* __restrict__ qkv_w,
                          const float* __restrict__ out_w,
                          const float* __restrict__ rpb_table,
                          const float* __restrict__ mask,
                          bf16* __restrict__ qkv_wb,
                          bf16* __restrict__ out_wb,
                          float* __restrict__ rpbx,
                          float* __restrict__ combo,
                          int build_combo) {
    int t = blockIdx.x * 256 + threadIdx.x;
    if (t < 110592) qkv_wb[t] = (bf16)qkv_w[t];
    if (t < 36864)  out_wb[t] = (bf16)out_w[t];
    if (t < 14406) {
        int h = t / 2401, ij = t % 2401, i = ij / 49, j = ij % 49;
        int ri = (i / 7 - j / 7 + 6) * 13 + (i % 7 - j % 7 + 6);
        rpbx[t] = rpb_table[ri * 6 + h];
    }
    if (build_combo && t < 64 * 6 * 64 * 64) {
        int j = t & 63, i = (t >> 6) & 63, r = t >> 12;
        int h = r % 6, w = r / 6;
        float v = -1e30f;
        if (i < 49 && j < 49) {
            int ri = (i / 7 - j / 7 + 6) * 13 + (i % 7 - j % 7 + 6);
            v = rpb_table[ri * 6 + h] + mask[w * 2401 + i * 49 + j];
        }
        combo[t] = v;
    }
}

// ======================= K1: QKV projection + attention =======================
// One window per block. Writes the 64x192 bf16 attention output (concat heads)
// into d_out's own per-window slot (first 24576 B of the 37632-B fp32 slot).
template <bool USE_COMBO>
__global__ __launch_bounds__(384, 2) void wmsa_qkatt(
    const float* __restrict__ x, const float* __restrict__ mask,
    const float* __restrict__ qkv_b,
    const bf16* __restrict__ qkv_wb,
    const float* __restrict__ rpbx, const float* __restrict__ combo,
    float* __restrict__ out)
{
    __shared__ __align__(16) bf16 s_qp[6][2048];   // q, then P (per head)
    __shared__ __align__(16) bf16 s_k [6][2048];
    __shared__ __align__(16) bf16 s_vt[6][2048];

    const int b    = blockIdx.x;
    const int tid  = threadIdx.x;
    const int wv   = tid >> 6;      // 0..5
    const int lane = tid & 63;
    const int lo   = lane & 15;
    const int hi   = lane >> 4;     // 0..3

    const float* xw    = x + (size_t)b * 9408;
    const int    obase = wv * 96;
    const int    sec   = wv >> 1;   // 0=q 1=k 2=v

    // ============ Phase 1: QKV = x @ qkv_w^T + qkv_b ============
#pragma unroll 1
    for (int mib = 0; mib < 2; ++mib) {
        f32x4 acc[2][6];
#pragma unroll
        for (int mi = 0; mi < 2; ++mi)
#pragma unroll
            for (int nj = 0; nj < 6; ++nj) acc[mi][nj] = (f32x4){0.f, 0.f, 0.f, 0.f};

        const int r0 = mib * 32 + lo;        // always < 49
        const int r1 = r0 + 16;              // mib=1: valid only if < 49

        auto loadA = [&](bf16x8& d0, bf16x8& d1, int kk) {
            const float* p0 = xw + r0 * 192 + kk * 32 + hi * 8;
            floatv4 f0 = *(const floatv4*)p0;
            floatv4 f1 = *(const floatv4*)(p0 + 4);
            d0[0]=(bf16)f0[0]; d0[1]=(bf16)f0[1]; d0[2]=(bf16)f0[2]; d0[3]=(bf16)f0[3];
            d0[4]=(bf16)f1[0]; d0[5]=(bf16)f1[1]; d0[6]=(bf16)f1[2]; d0[7]=(bf16)f1[3];
            floatv4 g0 = {0.f,0.f,0.f,0.f}, g1 = {0.f,0.f,0.f,0.f};
            if (r1 < 49) {
                const float* p1 = xw + r1 * 192 + kk * 32 + hi * 8;
                g0 = *(const floatv4*)p1;
                g1 = *(const floatv4*)(p1 + 4);
            }
            d1[0]=(bf16)g0[0]; d1[1]=(bf16)g0[1]; d1[2]=(bf16)g0[2]; d1[3]=(bf16)g0[3];
            d1[4]=(bf16)g1[0]; d1[5]=(bf16)g1[1]; d1[6]=(bf16)g1[2]; d1[7]=(bf16)g1[3];
        };

        bf16x8 a0, a1, na0, na1;
        loadA(a0, a1, 0);
#pragma unroll
        for (int kk = 0; kk < 6; ++kk) {
            if (kk < 5) loadA(na0, na1, kk + 1);
#pragma unroll
            for (int nj = 0; nj < 6; ++nj) {
                const int o = obase + nj * 16 + lo;
                bf16x8 bfr = *(const bf16x8*)(qkv_wb + o * 192 + kk * 32 + hi * 8);
                acc[0][nj] = __builtin_amdgcn_mfma_f32_16x16x32_bf16(a0, bfr, acc[0][nj], 0, 0, 0);
                acc[1][nj] = __builtin_amdgcn_mfma_f32_16x16x32_bf16(a1, bfr, acc[1][nj], 0, 0, 0);
            }
            a0 = na0; a1 = na1;
        }

        // epilogue: bias + scatter into q / k / v^T LDS tiles
#pragma unroll
        for (int nj = 0; nj < 6; ++nj) {
            const int o    = obase + nj * 16 + lo;
            const float bs = qkv_b[o];
            const int oc   = o - sec * 192;
            const int hh   = oc >> 5;
            const int dd   = oc & 31;
#pragma unroll
            for (int mi = 0; mi < 2; ++mi)
#pragma unroll
                for (int r = 0; r < 4; ++r) {
                    const int n = mib * 32 + mi * 16 + hi * 4 + r;
                    const float v = acc[mi][nj][r] + bs;
                    if (sec == 0)      *qk_ptr(&s_qp[hh][0], n, dd) = (bf16)(v * QK_SCALE);
                    else if (sec == 1) *qk_ptr(&s_k[hh][0], n, dd)  = (bf16)v;
                    else               *vt_ptr(&s_vt[hh][0], dd, n) = (bf16)v;
                }
        }
    }
    __syncthreads();

    // ============ Phase 2: attention, head h = wave id, 2 passes of 32 rows ===
    {
        const int h = wv;
        bf16* qb = &s_qp[h][0];
        bf16* kbase = &s_k[h][0];
        const float* cb = combo + (((size_t)(b & 63) * 6 + h) << 12);
        const float* mk = mask + (size_t)(b & 63) * 2401;
        const float* rb = rpbx + h * 2401;
        bf16* aobase = (bf16*)((char*)out + (size_t)b * 37632);   // bf16 ao slot

#pragma unroll
        for (int p = 0; p < 2; ++p) {
            const int rowb = p * 32;
            bf16x8 qa0 = *(const bf16x8*)qk_ptr(qb, rowb + lo, hi * 8);
            bf16x8 qa1 = *(const bf16x8*)qk_ptr(qb, rowb + 16 + lo, hi * 8);
            bf16x8 kb0 = *(const bf16x8*)qk_ptr(kbase, 0 + lo, hi * 8);
            bf16x8 kb1 = *(const bf16x8*)qk_ptr(kbase, 16 + lo, hi * 8);
            bf16x8 kb2 = *(const bf16x8*)qk_ptr(kbase, 32 + lo, hi * 8);
            bf16x8 kb3 = *(const bf16x8*)qk_ptr(kbase, 48 + lo, hi * 8);

            f32x4 s[2][4];
#pragma unroll
            for (int mi = 0; mi < 2; ++mi)
#pragma unroll
                for (int nt = 0; nt < 4; ++nt) s[mi][nt] = (f32x4){0.f, 0.f, 0.f, 0.f};
            s[0][0] = __builtin_amdgcn_mfma_f32_16x16x32_bf16(qa0, kb0, s[0][0], 0, 0, 0);
            s[0][1] = __builtin_amdgcn_mfma_f32_16x16x32_bf16(qa0, kb1, s[0][1], 0, 0, 0);
            s[0][2] = __builtin_amdgcn_mfma_f32_16x16x32_bf16(qa0, kb2, s[0][2], 0, 0, 0);
            s[0][3] = __builtin_amdgcn_mfma_f32_16x16x32_bf16(qa0, kb3, s[0][3], 0, 0, 0);
            s[1][0] = __builtin_amdgcn_mfma_f32_16x16x32_bf16(qa1, kb0, s[1][0], 0, 0, 0);
            s[1][1] = __builtin_amdgcn_mfma_f32_16x16x32_bf16(qa1, kb1, s[1][1], 0, 0, 0);
            s[1][2] = __builtin_amdgcn_mfma_f32_16x16x32_bf16(qa1, kb2, s[1][2], 0, 0, 0);
            s[1][3] = __builtin_amdgcn_mfma_f32_16x16x32_bf16(qa1, kb3, s[1][3], 0, 0, 0);

            // bias + mask
            if (USE_COMBO) {
#pragma unroll
                for (int nt = 0; nt < 4; ++nt) {
                    const int j = nt * 16 + lo;
#pragma unroll
                    for (int mi = 0; mi < 2; ++mi)
#pragma unroll
                        for (int r = 0; r < 4; ++r) {
                            const int i = rowb + mi * 16 + hi * 4 + r;
                            s[mi][nt][r] += cb[i * 64 + j];
                        }
                }
            } else {
#pragma unroll
                for (int nt = 0; nt < 4; ++nt) {
                    const int j = nt * 16 + lo;
#pragma unroll
                    for (int mi = 0; mi < 2; ++mi)
#pragma unroll
                        for (int r = 0; r < 4; ++r) {
                            const int i = rowb + mi * 16 + hi * 4 + r;
                            float sv = s[mi][nt][r];
                            if (j >= 49 || i >= 49) sv = -1e30f;
                            else sv += rb[i * 49 + j] + mk[i * 49 + j];
                            s[mi][nt][r] = sv;
                        }
                }
            }

            // softmax over j
#pragma unroll
            for (int mi = 0; mi < 2; ++mi)
#pragma unroll
                for (int r = 0; r < 4; ++r) {
                    float m = fmaxf(fmaxf(s[mi][0][r], s[mi][1][r]),
                                    fmaxf(s[mi][2][r], s[mi][3][r]));
                    m = fmaxf(m, __shfl_xor(m, 1));
                    m = fmaxf(m, __shfl_xor(m, 2));
                    m = fmaxf(m, __shfl_xor(m, 4));
                    m = fmaxf(m, __shfl_xor(m, 8));
                    float sum = 0.f;
#pragma unroll
                    for (int nt = 0; nt < 4; ++nt) {
                        float pv = __expf(s[mi][nt][r] - m);
                        s[mi][nt][r] = pv;
                        sum += pv;
                    }
                    sum += __shfl_xor(sum, 1);
                    sum += __shfl_xor(sum, 2);
                    sum += __shfl_xor(sum, 4);
                    sum += __shfl_xor(sum, 8);
                    const float inv = 1.0f / sum;
#pragma unroll
                    for (int nt = 0; nt < 4; ++nt) s[mi][nt][r] *= inv;
                }

            // PV for this pass; P staged over the pass's own (consumed) q rows
            f32x4 o00 = (f32x4){0.f,0.f,0.f,0.f}, o01 = (f32x4){0.f,0.f,0.f,0.f};
            f32x4 o10 = (f32x4){0.f,0.f,0.f,0.f}, o11 = (f32x4){0.f,0.f,0.f,0.f};
#pragma unroll
            for (int kk = 0; kk < 2; ++kk) {
#pragma unroll
                for (int mi = 0; mi < 2; ++mi)
#pragma unroll
                    for (int c = 0; c < 2; ++c) {
                        const int nt = kk * 2 + c;
#pragma unroll
                        for (int r = 0; r < 4; ++r)
                            *qk_ptr(qb, rowb + mi * 16 + hi * 4 + r, c * 16 + lo) =
                                (bf16)s[mi][nt][r];
                    }
                bf16x8 pa0 = *(const bf16x8*)qk_ptr(qb, rowb + lo, hi * 8);
                bf16x8 pa1 = *(const bf16x8*)qk_ptr(qb, rowb + 16 + lo, hi * 8);
                bf16x8 vb0 = *(const bf16x8*)vt_ptr(&s_vt[h][0], 0 + lo, kk * 32 + hi * 8);
                bf16x8 vb1 = *(const bf16x8*)vt_ptr(&s_vt[h][0], 16 + lo, kk * 32 + hi * 8);
                o00 = __builtin_amdgcn_mfma_f32_16x16x32_bf16(pa0, vb0, o00, 0, 0, 0);
                o10 = __builtin_amdgcn_mfma_f32_16x16x32_bf16(pa1, vb0, o10, 0, 0, 0);
                o01 = __builtin_amdgcn_mfma_f32_16x16x32_bf16(pa0, vb1, o01, 0, 0, 0);
                o11 = __builtin_amdgcn_mfma_f32_16x16x32_bf16(pa1, vb1, o11, 0, 0, 0);
            }

            // write this pass's 32x32 head-output block into the d_out ao slot
#pragma unroll
            for (int r = 0; r < 4; ++r) {
                const int n0 = rowb + hi * 4 + r;
                const int n1 = n0 + 16;
                aobase[n0 * 192 + h * 32 +  0 + lo] = (bf16)o00[r];
                aobase[n0 * 192 + h * 32 + 16 + lo] = (bf16)o01[r];
                aobase[n1 * 192 + h * 32 +  0 + lo] = (bf16)o10[r];
                aobase[n1 * 192 + h * 32 + 16 + lo] = (bf16)o11[r];
            }
        }
    }
}

// ======================= K2: output projection =======================
// Reads the bf16 ao tile from its own d_out slot into LDS, then overwrites the
// slot with the final fp32 result. Intra-block read-before-write; no cross-block
// overlap.
__global__ __launch_bounds__(384, 4) void wmsa_out(
    const bf16* __restrict__ out_wb, const float* __restrict__ out_b,
    float* __restrict__ out)
{
    __shared__ floatv4 s_ao4[1536];           // [64][192] bf16, chunk-swizzled
    bf16* s_ao = (bf16*)s_ao4;

    const int b    = blockIdx.x;
    const int tid  = threadIdx.x;
    const int wv   = tid >> 6;
    const int lane = tid & 63;
    const int lo   = lane & 15;
    const int hi   = lane >> 4;

    char* slot = (char*)out + (size_t)b * 37632;

    // cooperative coalesced load of 24576 B (1536 x 16B chunks)
    const floatv4* gsrc = (const floatv4*)slot;
#pragma unroll
    for (int q = 0; q < 4; ++q) {
        const int gc  = q * 384 + tid;        // 0..1535
        floatv4 val   = gsrc[gc];
        const int row = gc / 24;
        const int cc  = gc % 24;
        const int sc  = cc ^ (row & 7);
        *(floatv4*)&s_ao[(row * 24 + sc) * 8] = val;
    }
    __syncthreads();

    f32x4 facc[2][4];
#pragma unroll
    for (int t2 = 0; t2 < 2; ++t2)
#pragma unroll
        for (int mi = 0; mi < 4; ++mi) facc[t2][mi] = (f32x4){0.f, 0.f, 0.f, 0.f};

#pragma unroll
    for (int kk = 0; kk < 6; ++kk) {
        bf16x8 fa[4];
#pragma unroll
        for (int mi = 0; mi < 4; ++mi)
            fa[mi] = *(const bf16x8*)ao_ptr(s_ao, mi * 16 + lo, kk * 32 + hi * 8);
        bf16x8 fb0 = *(const bf16x8*)(out_wb + ((wv * 2 + 0) * 16 + lo) * 192 + kk * 32 + hi * 8);
        bf16x8 fb1 = *(const bf16x8*)(out_wb + ((wv * 2 + 1) * 16 + lo) * 192 + kk * 32 + hi * 8);
#pragma unroll
        for (int mi = 0; mi < 4; ++mi) {
            facc[0][mi] = __builtin_amdgcn_mfma_f32_16x16x32_bf16(fa[mi], fb0, facc[0][mi], 0, 0, 0);
            facc[1][mi] = __builtin_amdgcn_mfma_f32_16x16x32_bf16(fa[mi], fb1, facc[1][mi], 0, 0, 0);
        }
    }
    __syncthreads();   // all LDS (and slot) reads done before overwriting slot

    float* ow = (float*)slot;
#pragma unroll
    for (int t2 = 0; t2 < 2; ++t2) {
        const int o2 = (wv * 2 + t2) * 16 + lo;
        const float ob = out_b[o2];
#pragma unroll
        for (int mi = 0; mi < 4; ++mi)
#pragma unroll
            for (int r = 0; r < 4; ++r) {
                const int n = mi * 16 + hi * 4 + r;
                if (n < 49) ow[n * 192 + o2] = facc[t2][mi][r] + ob;
            }
    }
}

extern "C" void kernel_launch(void* const* d_in, const int* in_sizes, int n_in,
                              void* d_out, int out_size, void* d_ws, size_t ws_size,
                              hipStream_t stream) {
    const float* x      = (const float*)d_in[0];
    const float* mask   = (const float*)d_in[1];
    const float* qkv_w  = (const float*)d_in[2];
    const float* qkv_b  = (const float*)d_in[3];
    const float* out_w  = (const float*)d_in[4];
    const float* out_b  = (const float*)d_in[5];
    const float* rpb    = (const float*)d_in[6];
    float* out          = (float*)d_out;

    char* ws = (char*)d_ws;
    bf16*  qkv_wb = (bf16*)ws;                       // 110592 * 2 = 221184 B
    bf16*  out_wb = (bf16*)(ws + 221184);            //  36864 * 2 =  73728 B
    float* rpbx   = (float*)(ws + 294912);           //  14406 * 4 =  57624 B
    float* combo  = (float*)(ws + 352768);           // 1572864 * 4 = 6291456 B
    const bool use_combo = ws_size >= (size_t)(352768 + 6291456);

    hipLaunchKernelGGL(wmsa_prep, dim3(6144), dim3(256), 0, stream,
                       qkv_w, out_w, rpb, mask, qkv_wb, out_wb, rpbx, combo,
                       use_combo ? 1 : 0);
    if (use_combo)
        hipLaunchKernelGGL(HIP_KERNEL_NAME(wmsa_qkatt<true>), dim3(4096), dim3(384), 0, stream,
                           x, mask, qkv_b, qkv_wb, rpbx, combo, out);
    else
        hipLaunchKernelGGL(HIP_KERNEL_NAME(wmsa_qkatt<false>), dim3(4096), dim3(384), 0, stream,
                           x, mask, qkv_b, qkv_wb, rpbx, combo, out);
    hipLaunchKernelGGL(wmsa_out, dim3(4096), dim3(384), 0, stream,
                       out_wb, out_b, out);
}

// Round 6
// 473.428 us; speedup vs baseline: 2.0187x; 1.2640x over previous
//
#include <hip/hip_runtime.h>
#include <hip/hip_bf16.h>

typedef __bf16 bf16;
typedef __bf16 bf16x8 __attribute__((ext_vector_type(8)));
typedef float f32x4 __attribute__((ext_vector_type(4)));
typedef float floatv4 __attribute__((ext_vector_type(4)));

#define QK_SCALE 0.17677669529663687f

// ---- swizzled LDS addressing -------------------------------------------------
// q/k tiles: [64][32] bf16 per head (row = 64B = 4 x 16B chunks).
__device__ __forceinline__ bf16* qk_ptr(bf16* base, int row, int col) {
    return base + row * 32 + ((((col >> 3) ^ ((row >> 1) & 3)) << 3)) + (col & 7);
}
// vt tile: [32][64] bf16 per head (row = 128B = 8 chunks). chunk' = chunk ^ (row&7).
__device__ __forceinline__ bf16* vt_ptr(bf16* base, int row, int col) {
    return base + row * 64 + ((((col >> 3) ^ (row & 7)) << 3)) + (col & 7);
}
// ao tile: [64][192] bf16 (row = 384B = 24 chunks). chunk' = chunk ^ (row&7).
__device__ __forceinline__ bf16* ao_ptr(bf16* base, int row, int col) {
    return base + row * 192 + ((((col >> 3) ^ (row & 7)) << 3)) + (col & 7);
}

// ---------------- prep: weight bf16 convert + rpb expand + combo table --------
__global__ void wmsa_prep(const float* __restrict__ qkv_w,
                          const float* __restrict__ out_w,
                          const float* __restrict__ rpb_table,
                          const float* __restrict__ mask,
                          bf16* __restrict__ qkv_wb,
                          bf16* __restrict__ out_wb,
                          float* __restrict__ rpbx,
                          float* __restrict__ combo,
                          int build_combo) {
    int t = blockIdx.x * 256 + threadIdx.x;
    if (t < 110592) qkv_wb[t] = (bf16)qkv_w[t];
    if (t < 36864)  out_wb[t] = (bf16)out_w[t];
    if (t < 14406) {
        int h = t / 2401, ij = t % 2401, i = ij / 49, j = ij % 49;
        int ri = (i / 7 - j / 7 + 6) * 13 + (i % 7 - j % 7 + 6);
        rpbx[t] = rpb_table[ri * 6 + h];
    }
    if (build_combo && t < 64 * 6 * 64 * 64) {
        int j = t & 63, i = (t >> 6) & 63, r = t >> 12;
        int h = r % 6, w = r / 6;
        float v = -1e30f;
        if (i < 49 && j < 49) {
            int ri = (i / 7 - j / 7 + 6) * 13 + (i % 7 - j % 7 + 6);
            v = rpb_table[ri * 6 + h] + mask[w * 2401 + i * 49 + j];
        }
        combo[t] = v;
    }
}

// =================== fused kernel: one window per block, 12 waves =============
template <bool USE_COMBO>
__global__ __launch_bounds__(768, 3) void wmsa_fused(
    const float* __restrict__ x, const float* __restrict__ mask,
    const float* __restrict__ qkv_b, const float* __restrict__ out_b,
    const bf16* __restrict__ qkv_wb, const bf16* __restrict__ out_wb,
    const float* __restrict__ rpbx, const float* __restrict__ combo,
    float* __restrict__ out)
{
    __shared__ __align__(16) bf16 s_qp[6][2048];   // q, then P (per head)
    __shared__ __align__(16) bf16 s_kao[12288];    // k (per head), then ao[64][192]
    __shared__ __align__(16) bf16 s_vt[6][2048];   // v^T

    const int b    = blockIdx.x;
    const int tid  = threadIdx.x;
    const int wv   = tid >> 6;      // 0..11
    const int lane = tid & 63;
    const int lo   = lane & 15;
    const int hi   = lane >> 4;     // 0..3

    const float* xw    = x + (size_t)b * 9408;
    const int    obase = wv * 48;   // 48 output cols per wave
    const int    sec   = wv >> 2;   // 0=q 1=k 2=v (uniform per wave)

    // ============ Phase 1: QKV = x @ qkv_w^T + qkv_b (A and B double-buffered)
#pragma unroll 1
    for (int mib = 0; mib < 2; ++mib) {
        f32x4 acc[2][3];
#pragma unroll
        for (int mi = 0; mi < 2; ++mi)
#pragma unroll
            for (int nj = 0; nj < 3; ++nj) acc[mi][nj] = (f32x4){0.f, 0.f, 0.f, 0.f};

        const int r0 = mib * 32 + lo;        // always < 49
        const int r1 = r0 + 16;              // valid only if < 49

        auto loadA = [&](bf16x8& d0, bf16x8& d1, int kk) {
            const float* p0 = xw + r0 * 192 + kk * 32 + hi * 8;
            floatv4 f0 = *(const floatv4*)p0;
            floatv4 f1 = *(const floatv4*)(p0 + 4);
            d0[0]=(bf16)f0[0]; d0[1]=(bf16)f0[1]; d0[2]=(bf16)f0[2]; d0[3]=(bf16)f0[3];
            d0[4]=(bf16)f1[0]; d0[5]=(bf16)f1[1]; d0[6]=(bf16)f1[2]; d0[7]=(bf16)f1[3];
            floatv4 g0 = {0.f,0.f,0.f,0.f}, g1 = {0.f,0.f,0.f,0.f};
            if (r1 < 49) {
                const float* p1 = xw + r1 * 192 + kk * 32 + hi * 8;
                g0 = *(const floatv4*)p1;
                g1 = *(const floatv4*)(p1 + 4);
            }
            d1[0]=(bf16)g0[0]; d1[1]=(bf16)g0[1]; d1[2]=(bf16)g0[2]; d1[3]=(bf16)g0[3];
            d1[4]=(bf16)g1[0]; d1[5]=(bf16)g1[1]; d1[6]=(bf16)g1[2]; d1[7]=(bf16)g1[3];
        };
        auto loadB = [&](bf16x8* dst, int kk) {
#pragma unroll
            for (int nj = 0; nj < 3; ++nj)
                dst[nj] = *(const bf16x8*)(qkv_wb + (obase + nj * 16 + lo) * 192 + kk * 32 + hi * 8);
        };

        bf16x8 a0, a1, na0, na1, bc0, bc1, bc2, bn[3];
        {
            bf16x8 tmp[3];
            loadA(a0, a1, 0); loadB(tmp, 0);
            bc0 = tmp[0]; bc1 = tmp[1]; bc2 = tmp[2];
        }
#pragma unroll
        for (int kk = 0; kk < 6; ++kk) {
            if (kk < 5) { loadA(na0, na1, kk + 1); loadB(bn, kk + 1); }
            acc[0][0] = __builtin_amdgcn_mfma_f32_16x16x32_bf16(a0, bc0, acc[0][0], 0, 0, 0);
            acc[1][0] = __builtin_amdgcn_mfma_f32_16x16x32_bf16(a1, bc0, acc[1][0], 0, 0, 0);
            acc[0][1] = __builtin_amdgcn_mfma_f32_16x16x32_bf16(a0, bc1, acc[0][1], 0, 0, 0);
            acc[1][1] = __builtin_amdgcn_mfma_f32_16x16x32_bf16(a1, bc1, acc[1][1], 0, 0, 0);
            acc[0][2] = __builtin_amdgcn_mfma_f32_16x16x32_bf16(a0, bc2, acc[0][2], 0, 0, 0);
            acc[1][2] = __builtin_amdgcn_mfma_f32_16x16x32_bf16(a1, bc2, acc[1][2], 0, 0, 0);
            a0 = na0; a1 = na1; bc0 = bn[0]; bc1 = bn[1]; bc2 = bn[2];
        }

        // epilogue: bias + scatter into q / k / v^T LDS tiles
#pragma unroll
        for (int nj = 0; nj < 3; ++nj) {
            const int o    = obase + nj * 16 + lo;
            const float bs = qkv_b[o];
            const int oc   = o - sec * 192;
            const int hh   = oc >> 5;
            const int dd   = oc & 31;
#pragma unroll
            for (int mi = 0; mi < 2; ++mi)
#pragma unroll
                for (int r = 0; r < 4; ++r) {
                    const int n = mib * 32 + mi * 16 + hi * 4 + r;
                    const float v = acc[mi][nj][r] + bs;
                    if (sec == 0)      *qk_ptr(&s_qp[hh][0], n, dd)      = (bf16)(v * QK_SCALE);
                    else if (sec == 1) *qk_ptr(s_kao + hh * 2048, n, dd) = (bf16)v;
                    else               *vt_ptr(&s_vt[hh][0], dd, n)      = (bf16)v;
                }
        }
    }
    __syncthreads();

    // ============ Phase 2: attention. wave = (head h, 32-row pass p) ==========
    {
        const int h    = wv >> 1;    // 0..5
        const int p    = wv & 1;
        const int rowb = p * 32;
        bf16* qb    = &s_qp[h][0];
        bf16* kbase = s_kao + h * 2048;

        // issue combo loads early (longest latency first)
        f32x4 cv[2][4];
        if (USE_COMBO) {
            const float* cb = combo + (((size_t)(b & 63) * 6 + h) << 12);
#pragma unroll
            for (int mi = 0; mi < 2; ++mi)
#pragma unroll
                for (int nt = 0; nt < 4; ++nt)
#pragma unroll
                    for (int r = 0; r < 4; ++r)
                        cv[mi][nt][r] = cb[(rowb + mi * 16 + hi * 4 + r) * 64 + nt * 16 + lo];
        }

        bf16x8 qa0 = *(const bf16x8*)qk_ptr(qb, rowb + lo, hi * 8);
        bf16x8 qa1 = *(const bf16x8*)qk_ptr(qb, rowb + 16 + lo, hi * 8);
        bf16x8 kb0 = *(const bf16x8*)qk_ptr(kbase,  0 + lo, hi * 8);
        bf16x8 kb1 = *(const bf16x8*)qk_ptr(kbase, 16 + lo, hi * 8);
        bf16x8 kb2 = *(const bf16x8*)qk_ptr(kbase, 32 + lo, hi * 8);
        bf16x8 kb3 = *(const bf16x8*)qk_ptr(kbase, 48 + lo, hi * 8);

        // all q/k fragment reads complete -> P-staging and ao overlay are safe
        __syncthreads();

        f32x4 s[2][4];
#pragma unroll
        for (int mi = 0; mi < 2; ++mi)
#pragma unroll
            for (int nt = 0; nt < 4; ++nt) s[mi][nt] = (f32x4){0.f, 0.f, 0.f, 0.f};
        s[0][0] = __builtin_amdgcn_mfma_f32_16x16x32_bf16(qa0, kb0, s[0][0], 0, 0, 0);
        s[0][1] = __builtin_amdgcn_mfma_f32_16x16x32_bf16(qa0, kb1, s[0][1], 0, 0, 0);
        s[0][2] = __builtin_amdgcn_mfma_f32_16x16x32_bf16(qa0, kb2, s[0][2], 0, 0, 0);
        s[0][3] = __builtin_amdgcn_mfma_f32_16x16x32_bf16(qa0, kb3, s[0][3], 0, 0, 0);
        s[1][0] = __builtin_amdgcn_mfma_f32_16x16x32_bf16(qa1, kb0, s[1][0], 0, 0, 0);
        s[1][1] = __builtin_amdgcn_mfma_f32_16x16x32_bf16(qa1, kb1, s[1][1], 0, 0, 0);
        s[1][2] = __builtin_amdgcn_mfma_f32_16x16x32_bf16(qa1, kb2, s[1][2], 0, 0, 0);
        s[1][3] = __builtin_amdgcn_mfma_f32_16x16x32_bf16(qa1, kb3, s[1][3], 0, 0, 0);

        if (USE_COMBO) {
#pragma unroll
            for (int mi = 0; mi < 2; ++mi)
#pragma unroll
                for (int nt = 0; nt < 4; ++nt) s[mi][nt] += cv[mi][nt];
        } else {
            const float* mk = mask + (size_t)(b & 63) * 2401;
            const float* rb = rpbx + h * 2401;
#pragma unroll
            for (int nt = 0; nt < 4; ++nt) {
                const int j = nt * 16 + lo;
#pragma unroll
                for (int mi = 0; mi < 2; ++mi)
#pragma unroll
                    for (int r = 0; r < 4; ++r) {
                        const int i = rowb + mi * 16 + hi * 4 + r;
                        float sv = s[mi][nt][r];
                        if (j >= 49 || i >= 49) sv = -1e30f;
                        else sv += rb[i * 49 + j] + mk[i * 49 + j];
                        s[mi][nt][r] = sv;
                    }
            }
        }

        // softmax over j (64 cols = 4 regs x 16 lanes sharing hi)
#pragma unroll
        for (int mi = 0; mi < 2; ++mi)
#pragma unroll
            for (int r = 0; r < 4; ++r) {
                float m = fmaxf(fmaxf(s[mi][0][r], s[mi][1][r]),
                                fmaxf(s[mi][2][r], s[mi][3][r]));
                m = fmaxf(m, __shfl_xor(m, 1));
                m = fmaxf(m, __shfl_xor(m, 2));
                m = fmaxf(m, __shfl_xor(m, 4));
                m = fmaxf(m, __shfl_xor(m, 8));
                float sum = 0.f;
#pragma unroll
                for (int nt = 0; nt < 4; ++nt) {
                    float pv = __expf(s[mi][nt][r] - m);
                    s[mi][nt][r] = pv;
                    sum += pv;
                }
                sum += __shfl_xor(sum, 1);
                sum += __shfl_xor(sum, 2);
                sum += __shfl_xor(sum, 4);
                sum += __shfl_xor(sum, 8);
                const float inv = 1.0f / sum;
#pragma unroll
                for (int nt = 0; nt < 4; ++nt) s[mi][nt][r] *= inv;
            }

        // PV: rows rowb..rowb+31; P staged into this pass's own q rows
        f32x4 o00 = (f32x4){0.f,0.f,0.f,0.f}, o01 = (f32x4){0.f,0.f,0.f,0.f};
        f32x4 o10 = (f32x4){0.f,0.f,0.f,0.f}, o11 = (f32x4){0.f,0.f,0.f,0.f};
#pragma unroll
        for (int kk = 0; kk < 2; ++kk) {
#pragma unroll
            for (int mi = 0; mi < 2; ++mi)
#pragma unroll
                for (int c = 0; c < 2; ++c) {
                    const int nt = kk * 2 + c;
#pragma unroll
                    for (int r = 0; r < 4; ++r)
                        *qk_ptr(qb, rowb + mi * 16 + hi * 4 + r, c * 16 + lo) =
                            (bf16)s[mi][nt][r];
                }
            bf16x8 pa0 = *(const bf16x8*)qk_ptr(qb, rowb + lo, hi * 8);
            bf16x8 pa1 = *(const bf16x8*)qk_ptr(qb, rowb + 16 + lo, hi * 8);
            bf16x8 vb0 = *(const bf16x8*)vt_ptr(&s_vt[h][0],  0 + lo, kk * 32 + hi * 8);
            bf16x8 vb1 = *(const bf16x8*)vt_ptr(&s_vt[h][0], 16 + lo, kk * 32 + hi * 8);
            o00 = __builtin_amdgcn_mfma_f32_16x16x32_bf16(pa0, vb0, o00, 0, 0, 0);
            o10 = __builtin_amdgcn_mfma_f32_16x16x32_bf16(pa1, vb0, o10, 0, 0, 0);
            o01 = __builtin_amdgcn_mfma_f32_16x16x32_bf16(pa0, vb1, o01, 0, 0, 0);
            o11 = __builtin_amdgcn_mfma_f32_16x16x32_bf16(pa1, vb1, o11, 0, 0, 0);
        }

        // scatter head-output rows into ao (overlays k; safe post-barrier)
#pragma unroll
        for (int r = 0; r < 4; ++r) {
            const int n0 = rowb + hi * 4 + r;
            const int n1 = n0 + 16;
            *ao_ptr(s_kao, n0, h * 32 +  0 + lo) = (bf16)o00[r];
            *ao_ptr(s_kao, n0, h * 32 + 16 + lo) = (bf16)o01[r];
            *ao_ptr(s_kao, n1, h * 32 +  0 + lo) = (bf16)o10[r];
            *ao_ptr(s_kao, n1, h * 32 + 16 + lo) = (bf16)o11[r];
        }
    }
    __syncthreads();

    // ============ Phase 3: out = ao @ out_w^T + out_b (1 col-tile per wave) ===
    {
        const int o2 = wv * 16 + lo;           // 0..191
        f32x4 facc[4];
#pragma unroll
        for (int mi = 0; mi < 4; ++mi) facc[mi] = (f32x4){0.f, 0.f, 0.f, 0.f};

        bf16x8 fbc = *(const bf16x8*)(out_wb + o2 * 192 + hi * 8);
#pragma unroll
        for (int kk = 0; kk < 6; ++kk) {
            bf16x8 fbn;
            if (kk < 5) fbn = *(const bf16x8*)(out_wb + o2 * 192 + (kk + 1) * 32 + hi * 8);
            bf16x8 fa[4];
#pragma unroll
            for (int mi = 0; mi < 4; ++mi)
                fa[mi] = *(const bf16x8*)ao_ptr(s_kao, mi * 16 + lo, kk * 32 + hi * 8);
#pragma unroll
            for (int mi = 0; mi < 4; ++mi)
                facc[mi] = __builtin_amdgcn_mfma_f32_16x16x32_bf16(fa[mi], fbc, facc[mi], 0, 0, 0);
            fbc = fbn;
        }

        const float ob = out_b[o2];
        float* ow = out + (size_t)b * 9408;
#pragma unroll
        for (int mi = 0; mi < 4; ++mi)
#pragma unroll
            for (int r = 0; r < 4; ++r) {
                const int n = mi * 16 + hi * 4 + r;
                if (n < 49) ow[n * 192 + o2] = facc[mi][r] + ob;
            }
    }
}

extern "C" void kernel_launch(void* const* d_in, const int* in_sizes, int n_in,
                              void* d_out, int out_size, void* d_ws, size_t ws_size,
                              hipStream_t stream) {
    const float* x      = (const float*)d_in[0];
    const float* mask   = (const float*)d_in[1];
    const float* qkv_w  = (const float*)d_in[2];
    const float* qkv_b  = (const float*)d_in[3];
    const float* out_w  = (const float*)d_in[4];
    const float* out_b  = (const float*)d_in[5];
    const float* rpb    = (const float*)d_in[6];
    float* out          = (float*)d_out;

    char* ws = (char*)d_ws;
    bf16*  qkv_wb = (bf16*)ws;                       // 110592 * 2 = 221184 B
    bf16*  out_wb = (bf16*)(ws + 221184);            //  36864 * 2 =  73728 B
    float* rpbx   = (float*)(ws + 294912);           //  14406 * 4 =  57624 B
    float* combo  = (float*)(ws + 352768);           // 1572864 * 4 = 6291456 B
    const bool use_combo = ws_size >= (size_t)(352768 + 6291456);

    hipLaunchKernelGGL(wmsa_prep, dim3(6144), dim3(256), 0, stream,
                       qkv_w, out_w, rpb, mask, qkv_wb, out_wb, rpbx, combo,
                       use_combo ? 1 : 0);
    if (use_combo)
        hipLaunchKernelGGL(HIP_KERNEL_NAME(wmsa_fused<true>), dim3(4096), dim3(768), 0, stream,
                           x, mask, qkv_b, out_b, qkv_wb, out_wb, rpbx, combo, out);
    else
        hipLaunchKernelGGL(HIP_KERNEL_NAME(wmsa_fused<false>), dim3(4096), dim3(768), 0, stream,
                           x, mask, qkv_b, out_b, qkv_wb, out_wb, rpbx, combo, out);
}

// Round 7
// 308.954 us; speedup vs baseline: 3.0933x; 1.5324x over previous
//
#include <hip/hip_runtime.h>
#include <hip/hip_bf16.h>

typedef __bf16 bf16;
typedef __bf16 bf16x8 __attribute__((ext_vector_type(8)));
typedef float f32x4 __attribute__((ext_vector_type(4)));
typedef float floatv4 __attribute__((ext_vector_type(4)));

#define QK_SCALE 0.17677669529663687f

// ---- swizzled LDS addressing -------------------------------------------------
// q/k tiles: [64][32] bf16 per head (row = 64B = 4 x 16B chunks).
__device__ __forceinline__ bf16* qk_ptr(bf16* base, int row, int col) {
    return base + row * 32 + ((((col >> 3) ^ ((row >> 1) & 3)) << 3)) + (col & 7);
}
// vt tile: [32][64] bf16 per head (row = 128B = 8 chunks). chunk' = chunk ^ (row&7).
__device__ __forceinline__ bf16* vt_ptr(bf16* base, int row, int col) {
    return base + row * 64 + ((((col >> 3) ^ (row & 7)) << 3)) + (col & 7);
}
// 192-col tiles (x staging, ao): [64][192] bf16, 24 16B-chunks/row,
// chunk' = chunk ^ (row&7)  (XOR stays inside each 8-chunk group).
__device__ __forceinline__ bf16* ao_ptr(bf16* base, int row, int col) {
    return base + row * 192 + ((((col >> 3) ^ (row & 7)) << 3)) + (col & 7);
}

// ---------------- prep: weight bf16 convert + rpb expand + combo table --------
__global__ void wmsa_prep(const float* __restrict__ qkv_w,
                          const float* __restrict__ out_w,
                          const float* __restrict__ rpb_table,
                          const float* __restrict__ mask,
                          bf16* __restrict__ qkv_wb,
                          bf16* __restrict__ out_wb,
                          float* __restrict__ rpbx,
                          float* __restrict__ combo,
                          int build_combo) {
    int t = blockIdx.x * 256 + threadIdx.x;
    if (t < 110592) qkv_wb[t] = (bf16)qkv_w[t];
    if (t < 36864)  out_wb[t] = (bf16)out_w[t];
    if (t < 14406) {
        int h = t / 2401, ij = t % 2401, i = ij / 49, j = ij % 49;
        int ri = (i / 7 - j / 7 + 6) * 13 + (i % 7 - j % 7 + 6);
        rpbx[t] = rpb_table[ri * 6 + h];
    }
    if (build_combo && t < 64 * 6 * 64 * 64) {
        int j = t & 63, i = (t >> 6) & 63, r = t >> 12;
        int h = r % 6, w = r / 6;
        float v = -1e30f;
        if (i < 49 && j < 49) {
            int ri = (i / 7 - j / 7 + 6) * 13 + (i % 7 - j % 7 + 6);
            v = rpb_table[ri * 6 + h] + mask[w * 2401 + i * 49 + j];
        }
        combo[t] = v;
    }
}

// =================== fused kernel: one window per block, 12 waves =============
template <bool USE_COMBO>
__global__ __launch_bounds__(768, 3) void wmsa_fused(
    const float* __restrict__ x, const float* __restrict__ mask,
    const float* __restrict__ qkv_b, const float* __restrict__ out_b,
    const bf16* __restrict__ qkv_wb, const bf16* __restrict__ out_wb,
    const float* __restrict__ rpbx, const float* __restrict__ combo,
    float* __restrict__ out)
{
    __shared__ __align__(16) bf16 s_x[12288];      // x window bf16 [64][192] swz
    __shared__ __align__(16) bf16 s_qp[6][2048];   // q, then P (per head)
    __shared__ __align__(16) bf16 s_kao[12288];    // k (per head), then ao[64][192]
    __shared__ __align__(16) bf16 s_vt[6][2048];   // v^T

    const int b    = blockIdx.x;
    const int tid  = threadIdx.x;
    const int wv   = tid >> 6;      // 0..11
    const int lane = tid & 63;
    const int lo   = lane & 15;
    const int hi   = lane >> 4;     // 0..3

    const float* xw    = x + (size_t)b * 9408;
    const int    obase = wv * 48;   // 48 output cols per wave
    const int    sec   = wv >> 2;   // 0=q 1=k 2=v (uniform per wave)

    // ============ Phase 0: stage x (fp32 -> bf16) into LDS, zero-padded =======
    {
        // chunk c0 = tid: rows 0..31 (always valid)
        const int c0 = tid;
        const int r0s = c0 / 24, cc0 = c0 % 24;
        const float* p0 = xw + r0s * 192 + cc0 * 8;
        floatv4 f0 = *(const floatv4*)p0;
        floatv4 f1 = *(const floatv4*)(p0 + 4);
        bf16x8 v;
        v[0]=(bf16)f0[0]; v[1]=(bf16)f0[1]; v[2]=(bf16)f0[2]; v[3]=(bf16)f0[3];
        v[4]=(bf16)f1[0]; v[5]=(bf16)f1[1]; v[6]=(bf16)f1[2]; v[7]=(bf16)f1[3];
        *(bf16x8*)&s_x[(r0s * 24 + (cc0 ^ (r0s & 7))) * 8] = v;

        // chunk c1 = tid + 768: rows 32..63 (zero-fill rows >= 49)
        const int c1 = tid + 768;
        const int r1s = c1 / 24, cc1 = c1 % 24;
        bf16x8 w = {};
        if (r1s < 49) {
            const float* p1 = xw + r1s * 192 + cc1 * 8;
            floatv4 g0 = *(const floatv4*)p1;
            floatv4 g1 = *(const floatv4*)(p1 + 4);
            w[0]=(bf16)g0[0]; w[1]=(bf16)g0[1]; w[2]=(bf16)g0[2]; w[3]=(bf16)g0[3];
            w[4]=(bf16)g1[0]; w[5]=(bf16)g1[1]; w[6]=(bf16)g1[2]; w[7]=(bf16)g1[3];
        }
        *(bf16x8*)&s_x[(r1s * 24 + (cc1 ^ (r1s & 7))) * 8] = w;
    }
    __syncthreads();

    // ============ Phase 1: QKV = x @ qkv_w^T + qkv_b (A from LDS, B 2-deep) ===
#pragma unroll 1
    for (int mib = 0; mib < 2; ++mib) {
        f32x4 acc[2][3];
#pragma unroll
        for (int mi = 0; mi < 2; ++mi)
#pragma unroll
            for (int nj = 0; nj < 3; ++nj) acc[mi][nj] = (f32x4){0.f, 0.f, 0.f, 0.f};

        const int r0 = mib * 32 + lo;        // < 48
        const int r1 = r0 + 16;              // < 64 (rows >= 49 are zeros)

        auto loadB = [&](bf16x8* dst, int kk) {
#pragma unroll
            for (int nj = 0; nj < 3; ++nj)
                dst[nj] = *(const bf16x8*)(qkv_wb + (obase + nj * 16 + lo) * 192 + kk * 32 + hi * 8);
        };

        bf16x8 b0_[3], b1_[3], b2_[3];
        loadB(b0_, 0);
        loadB(b1_, 1);
#pragma unroll
        for (int kk = 0; kk < 6; ++kk) {
            if (kk < 4) loadB(b2_, kk + 2);
            bf16x8 a0 = *(const bf16x8*)ao_ptr(s_x, r0, kk * 32 + hi * 8);
            bf16x8 a1 = *(const bf16x8*)ao_ptr(s_x, r1, kk * 32 + hi * 8);
            acc[0][0] = __builtin_amdgcn_mfma_f32_16x16x32_bf16(a0, b0_[0], acc[0][0], 0, 0, 0);
            acc[1][0] = __builtin_amdgcn_mfma_f32_16x16x32_bf16(a1, b0_[0], acc[1][0], 0, 0, 0);
            acc[0][1] = __builtin_amdgcn_mfma_f32_16x16x32_bf16(a0, b0_[1], acc[0][1], 0, 0, 0);
            acc[1][1] = __builtin_amdgcn_mfma_f32_16x16x32_bf16(a1, b0_[1], acc[1][1], 0, 0, 0);
            acc[0][2] = __builtin_amdgcn_mfma_f32_16x16x32_bf16(a0, b0_[2], acc[0][2], 0, 0, 0);
            acc[1][2] = __builtin_amdgcn_mfma_f32_16x16x32_bf16(a1, b0_[2], acc[1][2], 0, 0, 0);
            b0_[0] = b1_[0]; b0_[1] = b1_[1]; b0_[2] = b1_[2];
            b1_[0] = b2_[0]; b1_[1] = b2_[1]; b1_[2] = b2_[2];
        }

        // epilogue: bias + scatter into q / k / v^T LDS tiles
#pragma unroll
        for (int nj = 0; nj < 3; ++nj) {
            const int o    = obase + nj * 16 + lo;
            const float bs = qkv_b[o];
            const int oc   = o - sec * 192;
            const int hh   = oc >> 5;
            const int dd   = oc & 31;
#pragma unroll
            for (int mi = 0; mi < 2; ++mi)
#pragma unroll
                for (int r = 0; r < 4; ++r) {
                    const int n = mib * 32 + mi * 16 + hi * 4 + r;
                    const float v = acc[mi][nj][r] + bs;
                    if (sec == 0)      *qk_ptr(&s_qp[hh][0], n, dd)      = (bf16)(v * QK_SCALE);
                    else if (sec == 1) *qk_ptr(s_kao + hh * 2048, n, dd) = (bf16)v;
                    else               *vt_ptr(&s_vt[hh][0], dd, n)      = (bf16)v;
                }
        }
    }
    __syncthreads();

    // ============ Phase 2: attention. wave = (head h, 32-row pass p) ==========
    {
        const int h    = wv >> 1;    // 0..5
        const int p    = wv & 1;
        const int rowb = p * 32;
        bf16* qb    = &s_qp[h][0];
        bf16* kbase = s_kao + h * 2048;

        // issue combo loads early (longest latency first)
        f32x4 cv[2][4];
        if (USE_COMBO) {
            const float* cb = combo + (((size_t)(b & 63) * 6 + h) << 12);
#pragma unroll
            for (int mi = 0; mi < 2; ++mi)
#pragma unroll
                for (int nt = 0; nt < 4; ++nt)
#pragma unroll
                    for (int r = 0; r < 4; ++r)
                        cv[mi][nt][r] = cb[(rowb + mi * 16 + hi * 4 + r) * 64 + nt * 16 + lo];
        }

        bf16x8 qa0 = *(const bf16x8*)qk_ptr(qb, rowb + lo, hi * 8);
        bf16x8 qa1 = *(const bf16x8*)qk_ptr(qb, rowb + 16 + lo, hi * 8);
        bf16x8 kb0 = *(const bf16x8*)qk_ptr(kbase,  0 + lo, hi * 8);
        bf16x8 kb1 = *(const bf16x8*)qk_ptr(kbase, 16 + lo, hi * 8);
        bf16x8 kb2 = *(const bf16x8*)qk_ptr(kbase, 32 + lo, hi * 8);
        bf16x8 kb3 = *(const bf16x8*)qk_ptr(kbase, 48 + lo, hi * 8);

        // all q/k fragment reads complete -> P-staging and ao overlay are safe
        __syncthreads();

        f32x4 s[2][4];
#pragma unroll
        for (int mi = 0; mi < 2; ++mi)
#pragma unroll
            for (int nt = 0; nt < 4; ++nt) s[mi][nt] = (f32x4){0.f, 0.f, 0.f, 0.f};
        s[0][0] = __builtin_amdgcn_mfma_f32_16x16x32_bf16(qa0, kb0, s[0][0], 0, 0, 0);
        s[0][1] = __builtin_amdgcn_mfma_f32_16x16x32_bf16(qa0, kb1, s[0][1], 0, 0, 0);
        s[0][2] = __builtin_amdgcn_mfma_f32_16x16x32_bf16(qa0, kb2, s[0][2], 0, 0, 0);
        s[0][3] = __builtin_amdgcn_mfma_f32_16x16x32_bf16(qa0, kb3, s[0][3], 0, 0, 0);
        s[1][0] = __builtin_amdgcn_mfma_f32_16x16x32_bf16(qa1, kb0, s[1][0], 0, 0, 0);
        s[1][1] = __builtin_amdgcn_mfma_f32_16x16x32_bf16(qa1, kb1, s[1][1], 0, 0, 0);
        s[1][2] = __builtin_amdgcn_mfma_f32_16x16x32_bf16(qa1, kb2, s[1][2], 0, 0, 0);
        s[1][3] = __builtin_amdgcn_mfma_f32_16x16x32_bf16(qa1, kb3, s[1][3], 0, 0, 0);

        if (USE_COMBO) {
#pragma unroll
            for (int mi = 0; mi < 2; ++mi)
#pragma unroll
                for (int nt = 0; nt < 4; ++nt) s[mi][nt] += cv[mi][nt];
        } else {
            const float* mk = mask + (size_t)(b & 63) * 2401;
            const float* rb = rpbx + h * 2401;
#pragma unroll
            for (int nt = 0; nt < 4; ++nt) {
                const int j = nt * 16 + lo;
#pragma unroll
                for (int mi = 0; mi < 2; ++mi)
#pragma unroll
                    for (int r = 0; r < 4; ++r) {
                        const int i = rowb + mi * 16 + hi * 4 + r;
                        float sv = s[mi][nt][r];
                        if (j >= 49 || i >= 49) sv = -1e30f;
                        else sv += rb[i * 49 + j] + mk[i * 49 + j];
                        s[mi][nt][r] = sv;
                    }
            }
        }

        // softmax over j (64 cols = 4 regs x 16 lanes sharing hi)
#pragma unroll
        for (int mi = 0; mi < 2; ++mi)
#pragma unroll
            for (int r = 0; r < 4; ++r) {
                float m = fmaxf(fmaxf(s[mi][0][r], s[mi][1][r]),
                                fmaxf(s[mi][2][r], s[mi][3][r]));
                m = fmaxf(m, __shfl_xor(m, 1));
                m = fmaxf(m, __shfl_xor(m, 2));
                m = fmaxf(m, __shfl_xor(m, 4));
                m = fmaxf(m, __shfl_xor(m, 8));
                float sum = 0.f;
#pragma unroll
                for (int nt = 0; nt < 4; ++nt) {
                    float pv = __expf(s[mi][nt][r] - m);
                    s[mi][nt][r] = pv;
                    sum += pv;
                }
                sum += __shfl_xor(sum, 1);
                sum += __shfl_xor(sum, 2);
                sum += __shfl_xor(sum, 4);
                sum += __shfl_xor(sum, 8);
                const float inv = 1.0f / sum;
#pragma unroll
                for (int nt = 0; nt < 4; ++nt) s[mi][nt][r] *= inv;
            }

        // PV: rows rowb..rowb+31; P staged into this pass's own q rows
        f32x4 o00 = (f32x4){0.f,0.f,0.f,0.f}, o01 = (f32x4){0.f,0.f,0.f,0.f};
        f32x4 o10 = (f32x4){0.f,0.f,0.f,0.f}, o11 = (f32x4){0.f,0.f,0.f,0.f};
#pragma unroll
        for (int kk = 0; kk < 2; ++kk) {
#pragma unroll
            for (int mi = 0; mi < 2; ++mi)
#pragma unroll
                for (int c = 0; c < 2; ++c) {
                    const int nt = kk * 2 + c;
#pragma unroll
                    for (int r = 0; r < 4; ++r)
                        *qk_ptr(qb, rowb + mi * 16 + hi * 4 + r, c * 16 + lo) =
                            (bf16)s[mi][nt][r];
                }
            bf16x8 pa0 = *(const bf16x8*)qk_ptr(qb, rowb + lo, hi * 8);
            bf16x8 pa1 = *(const bf16x8*)qk_ptr(qb, rowb + 16 + lo, hi * 8);
            bf16x8 vb0 = *(const bf16x8*)vt_ptr(&s_vt[h][0],  0 + lo, kk * 32 + hi * 8);
            bf16x8 vb1 = *(const bf16x8*)vt_ptr(&s_vt[h][0], 16 + lo, kk * 32 + hi * 8);
            o00 = __builtin_amdgcn_mfma_f32_16x16x32_bf16(pa0, vb0, o00, 0, 0, 0);
            o10 = __builtin_amdgcn_mfma_f32_16x16x32_bf16(pa1, vb0, o10, 0, 0, 0);
            o01 = __builtin_amdgcn_mfma_f32_16x16x32_bf16(pa0, vb1, o01, 0, 0, 0);
            o11 = __builtin_amdgcn_mfma_f32_16x16x32_bf16(pa1, vb1, o11, 0, 0, 0);
        }

        // scatter head-output rows into ao (overlays k; safe post-barrier)
#pragma unroll
        for (int r = 0; r < 4; ++r) {
            const int n0 = rowb + hi * 4 + r;
            const int n1 = n0 + 16;
            *ao_ptr(s_kao, n0, h * 32 +  0 + lo) = (bf16)o00[r];
            *ao_ptr(s_kao, n0, h * 32 + 16 + lo) = (bf16)o01[r];
            *ao_ptr(s_kao, n1, h * 32 +  0 + lo) = (bf16)o10[r];
            *ao_ptr(s_kao, n1, h * 32 + 16 + lo) = (bf16)o11[r];
        }
    }
    __syncthreads();

    // ============ Phase 3: out = ao @ out_w^T + out_b (1 col-tile per wave) ===
    {
        const int o2 = wv * 16 + lo;           // 0..191
        f32x4 facc[4];
#pragma unroll
        for (int mi = 0; mi < 4; ++mi) facc[mi] = (f32x4){0.f, 0.f, 0.f, 0.f};

        bf16x8 fbc = *(const bf16x8*)(out_wb + o2 * 192 + hi * 8);
#pragma unroll
        for (int kk = 0; kk < 6; ++kk) {
            bf16x8 fbn;
            if (kk < 5) fbn = *(const bf16x8*)(out_wb + o2 * 192 + (kk + 1) * 32 + hi * 8);
            bf16x8 fa[4];
#pragma unroll
            for (int mi = 0; mi < 4; ++mi)
                fa[mi] = *(const bf16x8*)ao_ptr(s_kao, mi * 16 + lo, kk * 32 + hi * 8);
#pragma unroll
            for (int mi = 0; mi < 4; ++mi)
                facc[mi] = __builtin_amdgcn_mfma_f32_16x16x32_bf16(fa[mi], fbc, facc[mi], 0, 0, 0);
            fbc = fbn;
        }

        const float ob = out_b[o2];
        float* ow = out + (size_t)b * 9408;
#pragma unroll
        for (int mi = 0; mi < 4; ++mi)
#pragma unroll
            for (int r = 0; r < 4; ++r) {
                const int n = mi * 16 + hi * 4 + r;
                if (n < 49) ow[n * 192 + o2] = facc[mi][r] + ob;
            }
    }
}

extern "C" void kernel_launch(void* const* d_in, const int* in_sizes, int n_in,
                              void* d_out, int out_size, void* d_ws, size_t ws_size,
                              hipStream_t stream) {
    const float* x      = (const float*)d_in[0];
    const float* mask   = (const float*)d_in[1];
    const float* qkv_w  = (const float*)d_in[2];
    const float* qkv_b  = (const float*)d_in[3];
    const float* out_w  = (const float*)d_in[4];
    const float* out_b  = (const float*)d_in[5];
    const float* rpb    = (const float*)d_in[6];
    float* out          = (float*)d_out;

    char* ws = (char*)d_ws;
    bf16*  qkv_wb = (bf16*)ws;                       // 110592 * 2 = 221184 B
    bf16*  out_wb = (bf16*)(ws + 221184);            //  36864 * 2 =  73728 B
    float* rpbx   = (float*)(ws + 294912);           //  14406 * 4 =  57624 B
    float* combo  = (float*)(ws + 352768);           // 1572864 * 4 = 6291456 B
    const bool use_combo = ws_size >= (size_t)(352768 + 6291456);

    hipLaunchKernelGGL(wmsa_prep, dim3(6144), dim3(256), 0, stream,
                       qkv_w, out_w, rpb, mask, qkv_wb, out_wb, rpbx, combo,
                       use_combo ? 1 : 0);
    if (use_combo)
        hipLaunchKernelGGL(HIP_KERNEL_NAME(wmsa_fused<true>), dim3(4096), dim3(768), 0, stream,
                           x, mask, qkv_b, out_b, qkv_wb, out_wb, rpbx, combo, out);
    else
        hipLaunchKernelGGL(HIP_KERNEL_NAME(wmsa_fused<false>), dim3(4096), dim3(768), 0, stream,
                           x, mask, qkv_b, out_b, qkv_wb, out_wb, rpbx, combo, out);
}